// Round 4
// baseline (113.404 us; speedup 1.0000x reference)
//
#include <hip/hip_runtime.h>
#include <math.h>

#define D_DIM 2048
#define M_EV  16384
#define LCH   32
#define CCH   (M_EV / LCH)      // 512 chunks
#define SEG   32                // chunks per scan segment
#define NSEG  (CCH / SEG)       // 16 segments
#define EPSEG (SEG * LCH)       // 1024 events per segment
#define BETA  1.0f
#define CPB   8                 // contrib-partial blocks (2048 events each)

__device__ __forceinline__ float softplus_f(float x){
  float e = __expf(-fabsf(x));
  return fmaxf(x, 0.0f) + __logf(1.0f + e);
}

// float -> bf16 (RNE); inputs are finite non-negative here.
__device__ __forceinline__ unsigned short f2bf(float f){
  unsigned b = __float_as_uint(f);
  return (unsigned short)((b + 0x7FFFu + ((b >> 16) & 1u)) >> 16);
}
__device__ __forceinline__ float bf2f(unsigned short u){
  return __uint_as_float(((unsigned)u) << 16);
}

// T_max arrives as a 1-element array; decode int-vs-float defensively.
__device__ __forceinline__ float decode_T(const void* p){
  unsigned bits = *(const unsigned*)p;
  float fv = __uint_as_float(bits);
  return (fv >= 1e-3f && fv <= 1e7f) ? fv : (float)(int)bits;
}

__device__ __forceinline__ float wave_red(float v){
  #pragma unroll
  for (int o = 32; o > 0; o >>= 1) v += __shfl_down(v, o);
  return v;
}

// k_prep (17 blocks, nothing pre-zeroed):
//   [0,8)  : muw = softplus(log_mu)+eps ; per-block mu partial -> acc[8+b]
//   [8,16) : contrib partials: 2048 events/block scattered into 8KB LDS
//            (LDS atomics), written non-atomic to Cpart[b-8][2048].
//   16     : acc[0..7] = 0.
__global__ __launch_bounds__(256) void k_prep(
    const float* __restrict__ t, const int* __restrict__ m,
    const float* __restrict__ log_mu, const void* Tp,
    float* __restrict__ muw, float* __restrict__ Cpart,
    float* __restrict__ acc)
{
  __shared__ float Cl[D_DIM];           // 8 KB
  __shared__ float red[4];
  const int b = blockIdx.x, tid = threadIdx.x;
  if (b < 8){
    int j = b*256 + tid;
    float v = softplus_f(log_mu[j]) + 1e-6f;
    muw[j] = v;
    float s = wave_red(v);
    if ((tid & 63) == 0) red[tid >> 6] = s;
    __syncthreads();
    if (tid == 0) acc[8 + b] = (red[0]+red[1]) + (red[2]+red[3]);
  } else if (b < 8 + CPB){
    float4* Cl4 = (float4*)Cl;
    const float4 z = make_float4(0.f,0.f,0.f,0.f);
    Cl4[tid*2] = z; Cl4[tid*2 + 1] = z;
    __syncthreads();
    const float T = decode_T(Tp);
    #pragma unroll
    for (int k = 0; k < 8; ++k){
      int i = (b-8)*2048 + k*256 + tid;
      atomicAdd(&Cl[m[i]], 1.0f - __expf(-BETA * (T - t[i])));
    }
    __syncthreads();
    float4* Cp4 = (float4*)(Cpart + (size_t)(b-8) * D_DIM);
    Cp4[tid*2]     = Cl4[tid*2];
    Cp4[tid*2 + 1] = Cl4[tid*2 + 1];
  } else {
    if (tid < 8) acc[tid] = 0.f;        // loglik, integral, -, ticket, ...
  }
}

// k_scan_alpha:
//   blocks [0,128): FUSED scatter+scan. Block (seg, jb) owns a
//   [32 chunk x 256 col] slice: reads the segment's 1024 raw events,
//   LDS-atomic scatters matching marks into a 32KB tile, scans the 32
//   chunks per-column in LDS, writes exclusive-scanned SL + Carry.
//   (SL is write-only here -> no unscanned round-trip, no dchunk buffer.)
//   blocks [128,640): sA = bf16(softplus(log_alpha)) + integral dot with
//   contrib (Cpart-summed), wave-reduced to ONE atomicAdd per block.
__global__ __launch_bounds__(256) void k_scan_alpha(
    const float* __restrict__ t, const int* __restrict__ m,
    float* __restrict__ SL, float* __restrict__ Carry,
    const float* __restrict__ la, const float* __restrict__ Cpart,
    unsigned short* __restrict__ sA, float* __restrict__ acc)
{
  __shared__ float Stile[SEG * 256];    // 32 KB
  __shared__ float tec[SEG];            // chunk-end times
  __shared__ float dch[SEG];            // chunk decay factors
  const int b = blockIdx.x, tid = threadIdx.x;
  if (b < 128){
    const int seg = b >> 3, jb = b & 7;
    {
      float4* S4 = (float4*)Stile;
      const float4 z = make_float4(0.f,0.f,0.f,0.f);
      #pragma unroll
      for (int k = 0; k < 8; ++k) S4[k*256 + tid] = z;
    }
    if (tid < SEG){
      int c = seg*SEG + tid;
      if (c < CCH-1){
        float te = t[(c+1)*LCH];
        tec[tid] = te;
        dch[tid] = __expf(t[c*LCH] - te);
      } else {
        tec[tid] = 0.f;                 // chunk 511: events skipped below
        dch[tid] = 1.0f;                // only affects unused Carry[15]
      }
    }
    __syncthreads();
    #pragma unroll
    for (int e = 0; e < 4; ++e){
      int il = e*256 + tid;             // local event index in segment
      int i  = seg*EPSEG + il;
      int cl = il >> 5;                 // local chunk 0..31
      int c  = seg*SEG + cl;
      int mk = m[i] - jb*256;
      if (c < CCH-1 && (unsigned)mk < 256u)
        atomicAdd(&Stile[cl*256 + mk], __expf(t[i] - tec[cl]));
    }
    __syncthreads();
    const int col = jb*256 + tid;
    float u = 0.f;
    #pragma unroll 4
    for (int cl = 0; cl < SEG; ++cl){
      int c = seg*SEG + cl;
      SL[(size_t)c * D_DIM + col] = u;
      u = fmaf(dch[cl], u, Stile[cl*256 + tid]);
    }
    Carry[(size_t)seg * D_DIM + col] = u;
    return;
  }
  const int nthreads = 512*256;               // alpha-range threads
  int atid = (b-128)*256 + tid;
  // this thread's fixed column-quad: sum the 8 contrib partials (L2-resident)
  const float4* Cp4 = (const float4*)Cpart;
  const int cq = atid & 511;                  // (atid*4 mod 2048)/4
  float4 cb = make_float4(0.f,0.f,0.f,0.f);
  #pragma unroll
  for (int r = 0; r < CPB; ++r){
    float4 v = Cp4[r*512 + cq];
    cb.x += v.x; cb.y += v.y; cb.z += v.z; cb.w += v.w;
  }
  const float4* la4 = (const float4*)la;
  ushort4* sA4 = (ushort4*)sA;
  float p = 0.f;
  #pragma unroll
  for (int u = 0; u < 8; ++u){
    int i4 = atid + u * nthreads;             // stride ≡ 0 mod row -> same cols
    float4 x = la4[i4];
    float4 sp;
    sp.x = softplus_f(x.x); sp.y = softplus_f(x.y);
    sp.z = softplus_f(x.z); sp.w = softplus_f(x.w);
    ushort4 h;
    h.x = f2bf(sp.x); h.y = f2bf(sp.y); h.z = f2bf(sp.z); h.w = f2bf(sp.w);
    sA4[i4] = h;
    p = fmaf(sp.x, cb.x, p);
    p = fmaf(sp.y, cb.y, p);
    p = fmaf(sp.z, cb.z, p);
    p = fmaf(sp.w, cb.w, p);
  }
  float w = wave_red(p);
  int lane = tid & 63, wid = tid >> 6;
  if (lane == 0) Stile[wid] = w;              // reuse LDS for reduction
  __syncthreads();
  if (tid == 0) atomicAdd(&acc[1], Stile[0]+Stile[1]+Stile[2]+Stile[3]);
}

// k_events: one block (512 thr = 8 waves) per chunk. Decomposed (no seq S):
//   lam_k = mu[d_k] + e^{-(t_k-t0)} * (sA[d_k] . S0)
//                   + sum_{i<k} e^{-(t_k-t_i)} * sA[d_k][m_i]
// E[seg] folded on the fly from Carry (backward weights); Aseg and cumdec
// computed locally from t (no buffers).
__global__ __launch_bounds__(512) void k_events(
    const float* __restrict__ t, const int* __restrict__ m,
    const unsigned short* __restrict__ sA, const float* __restrict__ muw,
    const float* __restrict__ SL, const float* __restrict__ Carry,
    float* __restrict__ acc, const void* Tp, float* __restrict__ out){
  __shared__ float S0[D_DIM];
  __shared__ float tl[LCH];
  __shared__ int   ml[LCH];
  __shared__ float wred[8];
  __shared__ float asg[16];
  const int tid = threadIdx.x;          // 0..511
  const int c = blockIdx.x;
  const int seg = c >> 5;

  if (tid < LCH){
    ml[tid] = m[c*LCH + tid];
    tl[tid] = t[c*LCH + tid];
  } else if (tid >= 64 && tid < 64 + NSEG - 1){
    int s = tid - 64;                   // s in [0,15): all the fold ever reads
    asg[s] = __expf(t[s*EPSEG] - t[(s+1)*EPSEG]);
  }
  __syncthreads();

  {
    const float cd = __expf(t[seg*EPSEG] - tl[0]);   // cumdec for this chunk
    const float4 sv = *(const float4*)(SL + (size_t)c * D_DIM + tid*4);
    float4 e = {0.f, 0.f, 0.f, 0.f};
    float wgt = 1.f;
    for (int s = seg - 1; s >= 0; --s){
      const float4 cr = *(const float4*)(Carry + (size_t)s * D_DIM + tid*4);
      e.x = fmaf(cr.x, wgt, e.x); e.y = fmaf(cr.y, wgt, e.y);
      e.z = fmaf(cr.z, wgt, e.z); e.w = fmaf(cr.w, wgt, e.w);
      wgt *= asg[s];
    }
    float4 s;
    s.x = fmaf(e.x, cd, sv.x); s.y = fmaf(e.y, cd, sv.y);
    s.z = fmaf(e.z, cd, sv.z); s.w = fmaf(e.w, cd, sv.w);
    *(float4*)&S0[tid*4] = s;
  }
  __syncthreads();

  const int l = tid & 63, w = tid >> 6;
  const int l4 = l * 4;

  // lane's 32 S0 columns -> registers (one-time)
  float4 s0[8];
  #pragma unroll
  for (int u = 0; u < 8; ++u) s0[u] = *(const float4*)&S0[u*256 + l4];

  const float t0 = tl[0];
  float lgw = 0.f;
  #pragma unroll
  for (int q = 0; q < 4; ++q){
    const int k = w*4 + q;
    const int d = ml[k];
    const unsigned short* row = sA + (size_t)d * D_DIM;
    float p = 0.f;
    #pragma unroll
    for (int u = 0; u < 8; ++u){
      ushort4 a = *(const ushort4*)(row + u*256 + l4);
      p = fmaf(bf2f(a.x), s0[u].x, p);
      p = fmaf(bf2f(a.y), s0[u].y, p);
      p = fmaf(bf2f(a.z), s0[u].z, p);
      p = fmaf(bf2f(a.w), s0[u].w, p);
    }
    const float tk = tl[k];
    float g = 0.f;
    if (l < k) g = bf2f(row[ml[l]]) * __expf(tl[l] - tk);  // exact pair term
    p = fmaf(p, __expf(t0 - tk), g);
    float v = wave_red(p);
    if (l == 0) lgw += __logf(muw[d] + v + 1e-8f);
  }
  if (l == 0) wred[w] = lgw;
  __syncthreads();
  if (tid == 0){
    float lg = ((wred[0]+wred[1])+(wred[2]+wred[3]))
             + ((wred[4]+wred[5])+(wred[6]+wred[7]));
    atomicAdd(&acc[0], lg);
    __threadfence();                        // publish before taking ticket
    unsigned old = atomicAdd((unsigned*)&acc[3], 1u);
    if (old == CCH - 1){                    // last block: finalize
      float a0 = atomicAdd(&acc[0], 0.0f);  // device-scope reads
      float a1 = atomicAdd(&acc[1], 0.0f);
      float musum = 0.f;
      #pragma unroll
      for (int j = 8; j < 16; ++j) musum += atomicAdd(&acc[j], 0.0f);
      float T = decode_T(Tp);
      out[0] = a0 - (T * musum + a1 * (1.0f / BETA));
    }
  }
}

extern "C" void kernel_launch(void* const* d_in, const int* in_sizes, int n_in,
                              void* d_out, int out_size, void* d_ws, size_t ws_size,
                              hipStream_t stream) {
  const float* t_events  = (const float*)d_in[0];
  const int*   marks     = (const int*)  d_in[1];
  const void*  Tp        =               d_in[2];
  const float* log_mu    = (const float*)d_in[3];
  const float* log_alpha = (const float*)d_in[4];
  float* out = (float*)d_out;

  // ws layout (floats) — nothing requires pre-zeroing:
  // SL[CCH*D] | Carry[NSEG*D] | muw[D] | Cpart[CPB*D] | acc[16] | sA[D*D bf16]
  float* ws      = (float*)d_ws;
  float* SL      = ws;
  float* Carry   = SL + (size_t)CCH * D_DIM;
  float* muw     = Carry + (size_t)NSEG * D_DIM;
  float* Cpart   = muw + D_DIM;
  float* acc     = Cpart + (size_t)CPB * D_DIM;
  unsigned short* sA = (unsigned short*)(acc + 16);   // 16B-aligned offset

  k_prep      <<<17, 256, 0, stream>>>(t_events, marks, log_mu, Tp,
                                       muw, Cpart, acc);
  k_scan_alpha<<<640, 256, 0, stream>>>(t_events, marks, SL, Carry,
                                        log_alpha, Cpart, sA, acc);
  k_events    <<<CCH, 512, 0, stream>>>(t_events, marks, sA, muw, SL, Carry,
                                        acc, Tp, out);
}

// Round 5
// 112.716 us; speedup vs baseline: 1.0061x; 1.0061x over previous
//
#include <hip/hip_runtime.h>
#include <math.h>

#define D_DIM 2048
#define M_EV  16384
#define LCH   32
#define CCH   (M_EV / LCH)      // 512 chunks
#define SEG   32                // chunks per scan segment
#define NSEG  (CCH / SEG)       // 16 segments
#define EPSEG (SEG * LCH)       // 1024 events per segment
#define BETA  1.0f
#define CPB   8                 // contrib-partial blocks (2048 events each)

__device__ __forceinline__ float softplus_f(float x){
  float e = __expf(-fabsf(x));
  return fmaxf(x, 0.0f) + __logf(1.0f + e);
}

// float -> bf16 (RNE); inputs are finite non-negative here.
__device__ __forceinline__ unsigned short f2bf(float f){
  unsigned b = __float_as_uint(f);
  return (unsigned short)((b + 0x7FFFu + ((b >> 16) & 1u)) >> 16);
}
__device__ __forceinline__ float bf2f(unsigned short u){
  return __uint_as_float(((unsigned)u) << 16);
}

// T_max arrives as a 1-element array; decode int-vs-float defensively.
__device__ __forceinline__ float decode_T(const void* p){
  unsigned bits = *(const unsigned*)p;
  float fv = __uint_as_float(bits);
  return (fv >= 1e-3f && fv <= 1e7f) ? fv : (float)(int)bits;
}

__device__ __forceinline__ float wave_red(float v){
  #pragma unroll
  for (int o = 32; o > 0; o >>= 1) v += __shfl_down(v, o);
  return v;
}

// k_prep (32 blocks, nothing pre-zeroed):
//   [0,8)   : muw = softplus(log_mu)+eps ; per-block mu partial -> acc[8+b]
//   [8,16)  : contrib partials: 2048 events/block scattered into 8KB LDS
//             (LDS atomics), written non-atomic to Cpart[b-8][2048].
//   [16,31) : Carry[seg], seg = b-16 in [0,15): direct exponentials
//             Carry[seg][j] = sum_{i in seg} e^{t_i - t_next_seg_start}[m_i=j]
//             via LDS-atomic scatter. (Carry[15] is never read.)
//   31      : acc[0..7] = 0.
__global__ __launch_bounds__(256) void k_prep(
    const float* __restrict__ t, const int* __restrict__ m,
    const float* __restrict__ log_mu, const void* Tp,
    float* __restrict__ muw, float* __restrict__ Cpart,
    float* __restrict__ Carry, float* __restrict__ acc)
{
  __shared__ float Cl[D_DIM];           // 8 KB
  __shared__ float red[4];
  const int b = blockIdx.x, tid = threadIdx.x;
  if (b < 8){
    int j = b*256 + tid;
    float v = softplus_f(log_mu[j]) + 1e-6f;
    muw[j] = v;
    float s = wave_red(v);
    if ((tid & 63) == 0) red[tid >> 6] = s;
    __syncthreads();
    if (tid == 0) acc[8 + b] = (red[0]+red[1]) + (red[2]+red[3]);
  } else if (b < 8 + CPB){
    float4* Cl4 = (float4*)Cl;
    const float4 z = make_float4(0.f,0.f,0.f,0.f);
    Cl4[tid*2] = z; Cl4[tid*2 + 1] = z;
    __syncthreads();
    const float T = decode_T(Tp);
    #pragma unroll
    for (int k = 0; k < 8; ++k){
      int i = (b-8)*2048 + k*256 + tid;
      atomicAdd(&Cl[m[i]], 1.0f - __expf(-BETA * (T - t[i])));
    }
    __syncthreads();
    float4* Cp4 = (float4*)(Cpart + (size_t)(b-8) * D_DIM);
    Cp4[tid*2]     = Cl4[tid*2];
    Cp4[tid*2 + 1] = Cl4[tid*2 + 1];
  } else if (b < 31){
    const int seg = b - 16;               // 0..14
    float4* Cl4 = (float4*)Cl;
    const float4 z = make_float4(0.f,0.f,0.f,0.f);
    Cl4[tid*2] = z; Cl4[tid*2 + 1] = z;
    __syncthreads();
    const float te = t[(seg+1)*EPSEG];    // next segment start
    #pragma unroll
    for (int k = 0; k < 4; ++k){
      int i = seg*EPSEG + k*256 + tid;
      atomicAdd(&Cl[m[i]], __expf(t[i] - te));
    }
    __syncthreads();
    float4* Cr4 = (float4*)(Carry + (size_t)seg * D_DIM);
    Cr4[tid*2]     = Cl4[tid*2];
    Cr4[tid*2 + 1] = Cl4[tid*2 + 1];
  } else {
    if (tid < 8) acc[tid] = 0.f;          // loglik, integral, -, ticket, ...
  }
}

// k_alpha (pure streaming, 512 blocks): sA = bf16(softplus(log_alpha)) +
// integral dot with contrib (Cpart-summed), wave-reduced to ONE atomicAdd
// per block (acc[1]).
__global__ __launch_bounds__(256) void k_alpha(
    const float* __restrict__ la, const float* __restrict__ Cpart,
    unsigned short* __restrict__ sA, float* __restrict__ acc)
{
  const int b = blockIdx.x, tid = threadIdx.x;
  const int nthreads = 512*256;
  int atid = b*256 + tid;
  // this thread's fixed column-quad: sum the 8 contrib partials (L2-resident)
  const float4* Cp4 = (const float4*)Cpart;
  const int cq = atid & 511;                  // (atid*4 mod 2048)/4
  float4 cb = make_float4(0.f,0.f,0.f,0.f);
  #pragma unroll
  for (int r = 0; r < CPB; ++r){
    float4 v = Cp4[r*512 + cq];
    cb.x += v.x; cb.y += v.y; cb.z += v.z; cb.w += v.w;
  }
  const float4* la4 = (const float4*)la;
  ushort4* sA4 = (ushort4*)sA;
  float p = 0.f;
  #pragma unroll
  for (int u = 0; u < 8; ++u){
    int i4 = atid + u * nthreads;             // stride ≡ 0 mod row -> same cols
    float4 x = la4[i4];
    float4 sp;
    sp.x = softplus_f(x.x); sp.y = softplus_f(x.y);
    sp.z = softplus_f(x.z); sp.w = softplus_f(x.w);
    ushort4 h;
    h.x = f2bf(sp.x); h.y = f2bf(sp.y); h.z = f2bf(sp.z); h.w = f2bf(sp.w);
    sA4[i4] = h;
    p = fmaf(sp.x, cb.x, p);
    p = fmaf(sp.y, cb.y, p);
    p = fmaf(sp.z, cb.z, p);
    p = fmaf(sp.w, cb.w, p);
  }
  __shared__ float red[4];
  float w = wave_red(p);
  int lane = tid & 63, wid = tid >> 6;
  if (lane == 0) red[wid] = w;
  __syncthreads();
  if (tid == 0) atomicAdd(&acc[1], red[0]+red[1]+red[2]+red[3]);
}

// k_events: one block (512 thr = 8 waves) per chunk. Decomposed (no seq S):
//   lam_k = mu[d_k] + e^{-(t_k-t0)} * (sA[d_k] . S0)
//                   + sum_{i<k} e^{-(t_k-t_i)} * sA[d_k][m_i]
// S0 built IN-BLOCK by direct-exponential scatter of the <=992 preceding
// in-segment events (no SL buffer), plus the Carry fold (backward weights);
// Aseg/cumdec computed locally from t.
__global__ __launch_bounds__(512) void k_events(
    const float* __restrict__ t, const int* __restrict__ m,
    const unsigned short* __restrict__ sA, const float* __restrict__ muw,
    const float* __restrict__ Carry, float* __restrict__ acc,
    const void* Tp, float* __restrict__ out){
  __shared__ float S0[D_DIM];
  __shared__ float tl[LCH];
  __shared__ int   ml[LCH];
  __shared__ float wred[8];
  __shared__ float asg[16];
  const int tid = threadIdx.x;          // 0..511
  const int c = blockIdx.x;
  const int seg = c >> 5;

  *(float4*)&S0[tid*4] = make_float4(0.f,0.f,0.f,0.f);
  if (tid < LCH){
    ml[tid] = m[c*LCH + tid];
    tl[tid] = t[c*LCH + tid];
  } else if (tid >= 64 && tid < 64 + NSEG - 1){
    int s = tid - 64;                   // s in [0,15): all the fold ever reads
    asg[s] = __expf(t[s*EPSEG] - t[(s+1)*EPSEG]);
  }
  __syncthreads();

  const float t0 = tl[0];
  // scatter preceding in-segment events: S0[m_i] += e^{t_i - t0}
  const int nev = (c & 31) * LCH;       // 0..992
  for (int il = tid; il < nev; il += 512){
    int i = seg*EPSEG + il;
    atomicAdd(&S0[m[i]], __expf(t[i] - t0));
  }
  __syncthreads();

  {
    const float cd = __expf(t[seg*EPSEG] - t0);   // cumdec for this chunk
    float4 e = {0.f, 0.f, 0.f, 0.f};
    float wgt = 1.f;
    for (int s = seg - 1; s >= 0; --s){
      const float4 cr = *(const float4*)(Carry + (size_t)s * D_DIM + tid*4);
      e.x = fmaf(cr.x, wgt, e.x); e.y = fmaf(cr.y, wgt, e.y);
      e.z = fmaf(cr.z, wgt, e.z); e.w = fmaf(cr.w, wgt, e.w);
      wgt *= asg[s];
    }
    float4 sv = *(float4*)&S0[tid*4];
    sv.x = fmaf(e.x, cd, sv.x); sv.y = fmaf(e.y, cd, sv.y);
    sv.z = fmaf(e.z, cd, sv.z); sv.w = fmaf(e.w, cd, sv.w);
    *(float4*)&S0[tid*4] = sv;
  }
  __syncthreads();

  const int l = tid & 63, w = tid >> 6;
  const int l4 = l * 4;

  // lane's 32 S0 columns -> registers (one-time)
  float4 s0[8];
  #pragma unroll
  for (int u = 0; u < 8; ++u) s0[u] = *(const float4*)&S0[u*256 + l4];

  float lgw = 0.f;
  #pragma unroll
  for (int q = 0; q < 4; ++q){
    const int k = w*4 + q;
    const int d = ml[k];
    const unsigned short* row = sA + (size_t)d * D_DIM;
    float p = 0.f;
    #pragma unroll
    for (int u = 0; u < 8; ++u){
      ushort4 a = *(const ushort4*)(row + u*256 + l4);
      p = fmaf(bf2f(a.x), s0[u].x, p);
      p = fmaf(bf2f(a.y), s0[u].y, p);
      p = fmaf(bf2f(a.z), s0[u].z, p);
      p = fmaf(bf2f(a.w), s0[u].w, p);
    }
    const float tk = tl[k];
    float g = 0.f;
    if (l < k) g = bf2f(row[ml[l]]) * __expf(tl[l] - tk);  // exact pair term
    p = fmaf(p, __expf(t0 - tk), g);
    float v = wave_red(p);
    if (l == 0) lgw += __logf(muw[d] + v + 1e-8f);
  }
  if (l == 0) wred[w] = lgw;
  __syncthreads();
  if (tid == 0){
    float lg = ((wred[0]+wred[1])+(wred[2]+wred[3]))
             + ((wred[4]+wred[5])+(wred[6]+wred[7]));
    atomicAdd(&acc[0], lg);
    __threadfence();                        // publish before taking ticket
    unsigned old = atomicAdd((unsigned*)&acc[3], 1u);
    if (old == CCH - 1){                    // last block: finalize
      float a0 = atomicAdd(&acc[0], 0.0f);  // device-scope reads
      float a1 = atomicAdd(&acc[1], 0.0f);
      float musum = 0.f;
      #pragma unroll
      for (int j = 8; j < 16; ++j) musum += atomicAdd(&acc[j], 0.0f);
      float T = decode_T(Tp);
      out[0] = a0 - (T * musum + a1 * (1.0f / BETA));
    }
  }
}

extern "C" void kernel_launch(void* const* d_in, const int* in_sizes, int n_in,
                              void* d_out, int out_size, void* d_ws, size_t ws_size,
                              hipStream_t stream) {
  const float* t_events  = (const float*)d_in[0];
  const int*   marks     = (const int*)  d_in[1];
  const void*  Tp        =               d_in[2];
  const float* log_mu    = (const float*)d_in[3];
  const float* log_alpha = (const float*)d_in[4];
  float* out = (float*)d_out;

  // ws layout (floats) — nothing requires pre-zeroing:
  // Carry[NSEG*D] | muw[D] | Cpart[CPB*D] | acc[16] | sA[D*D bf16]
  float* ws      = (float*)d_ws;
  float* Carry   = ws;
  float* muw     = Carry + (size_t)NSEG * D_DIM;
  float* Cpart   = muw + D_DIM;
  float* acc     = Cpart + (size_t)CPB * D_DIM;
  unsigned short* sA = (unsigned short*)(acc + 16);   // 16B-aligned offset

  k_prep  <<<32, 256, 0, stream>>>(t_events, marks, log_mu, Tp,
                                   muw, Cpart, Carry, acc);
  k_alpha <<<512, 256, 0, stream>>>(log_alpha, Cpart, sA, acc);
  k_events<<<CCH, 512, 0, stream>>>(t_events, marks, sA, muw, Carry,
                                    acc, Tp, out);
}